// Round 9
// baseline (163.696 us; speedup 1.0000x reference)
//
#include <hip/hip_runtime.h>
#include <stdint.h>

#define SPARSE_D 41
#define SPARSE_H 1600
#define SPARSE_W 1408
#define BN_EPS 0.001f

static constexpr int NYB = SPARSE_H / 2;          // 800
static constexpr int NBUCKET = SPARSE_D * NYB;    // 32,800
static constexpr int PCAP = 12;                   // max non-self pairs per voxel (lambda~0.056)

// bucket = z*NYB + (y>>1): 32 uint32 words (128B). word0 = count, words 1..31 = entries.
// entry: [29]=y&1, [28:18]=x (11b), [17:0]=idx
// pairs slot0 word: [27:24]=cnt, [22:18]=k, [17:0]=idx ; rows >=1: [22:18]=k,[17:0]=idx

// ---------------- scatter voxels into buckets (count in word0) ----------------
__global__ void k_insert(const int* __restrict__ coords, uint32_t* __restrict__ bent, int N) {
    int n = blockIdx.x * blockDim.x + threadIdx.x;
    if (n >= N) return;
    int4 c4 = ((const int4*)coords)[n];
    int z = c4.y, y = c4.z, x = c4.w;
    int b = z * NYB + (y >> 1);
    uint32_t e = ((uint32_t)(y & 1) << 29) | ((uint32_t)x << 18) | (uint32_t)n;
    int slot = atomicAdd((int*)&bent[(size_t)b * 32], 1) + 1;
    if (slot <= 31) bent[(size_t)b * 32 + slot] = e;
}

// ---- stats epilogue: wave shuffle reduce -> LDS -> per-block partials ----
__device__ __forceinline__ void stats_epilogue(const float acc[16],
                                               float* __restrict__ partials,
                                               float (*sred)[32]) {
    int lid = threadIdx.x & 63;
    int wid = threadIdx.x >> 6;
    #pragma unroll
    for (int d = 0; d < 16; ++d) {
        float v = acc[d];
        float v2 = v * v;
        #pragma unroll
        for (int off = 32; off; off >>= 1) {
            v += __shfl_xor(v, off);
            v2 += __shfl_xor(v2, off);
        }
        if (lid == 0) { sred[wid][d] = v; sred[wid][16 + d] = v2; }
    }
    __syncthreads();
    if (threadIdx.x < 32)
        partials[(size_t)blockIdx.x * 32 + threadIdx.x] =
            sred[0][threadIdx.x] + sred[1][threadIdx.x] +
            sred[2][threadIdx.x] + sred[3][threadIdx.x];
}

// ---- redundant reduce of partials -> scale/shift (used by fused bnrelu) ----
__device__ __forceinline__ void reduce_scsh(const float* __restrict__ partials, int nbp,
                                            const float* __restrict__ gamma,
                                            const float* __restrict__ beta,
                                            float invN, float (*red)[33],
                                            float* __restrict__ scsh) {
    int ch = threadIdx.x & 31;
    int rg = threadIdx.x >> 5;    // 0..7
    float s0 = 0.f, s1 = 0.f, s2 = 0.f, s3 = 0.f;
    int j = rg;
    for (; j + 24 < nbp; j += 32) {
        s0 += partials[(size_t)(j     ) * 32 + ch];
        s1 += partials[(size_t)(j +  8) * 32 + ch];
        s2 += partials[(size_t)(j + 16) * 32 + ch];
        s3 += partials[(size_t)(j + 24) * 32 + ch];
    }
    for (; j < nbp; j += 8) s0 += partials[(size_t)j * 32 + ch];
    red[rg][ch] = (s0 + s1) + (s2 + s3);
    __syncthreads();
    if (threadIdx.x < 32) {
        float t = 0.f;
        #pragma unroll
        for (int r = 0; r < 8; ++r) t += red[r][threadIdx.x];
        red[0][threadIdx.x] = t;
    }
    __syncthreads();
    if (threadIdx.x < 16) {
        int d = threadIdx.x;
        float mean = red[0][d] * invN;
        float var  = red[0][16 + d] * invN - mean * mean;
        float sc = gamma[d] * rsqrtf(var + BN_EPS);
        scsh[d] = sc;
        scsh[16 + d] = beta[d] - mean * sc;
    }
    __syncthreads();
}

// ------ fused: build pairs + conv1 (C=3->16) + BN1 stats; LDS-staged h1 store ------
__global__ void k_build_conv1(const int* __restrict__ coords, const uint32_t* __restrict__ bent,
                              const float* __restrict__ feat, const float* __restrict__ w1,
                              uint32_t* __restrict__ pairs,
                              float* __restrict__ h1, float* __restrict__ partials, int N) {
    __shared__ float sred[4][32];
    __shared__ float4 stage[256 * 4];      // 16 KB: block's h1 tile
    int n = blockIdx.x * blockDim.x + threadIdx.x;
    float acc[16];
    #pragma unroll
    for (int d = 0; d < 16; ++d) acc[d] = 0.f;
    if (n < N) {
        int4 c4 = ((const int4*)coords)[n];
        int z = c4.y, y = c4.z, x = c4.w;

        float f0 = feat[n * 3 + 0], f1 = feat[n * 3 + 1], f2 = feat[n * 3 + 2];
        const float* wd = w1 + 13 * 48;
        #pragma unroll
        for (int d = 0; d < 16; ++d)
            acc[d] = fmaf(f0, wd[d], fmaf(f1, wd[16 + d], f2 * wd[32 + d]));

        // preload all 6 bucket line0s unconditionally (masked -> bucket 0)
        int yb0 = (y - 1) >> 1;
        uint4 q0[6];
        int bix[6], mm[6];
        #pragma unroll
        for (int p = 0; p < 6; ++p) {
            int zz = z + p / 2 - 1;
            int yb = yb0 + (p & 1);
            bool v = ((unsigned)zz < SPARSE_D) & ((unsigned)yb < NYB);
            int b = v ? (zz * NYB + yb) : 0;
            bix[p] = b;
            q0[p] = *(const uint4*)&bent[(size_t)b * 32];
            mm[p] = v ? 1 : 0;
        }

        uint32_t lpairs[PCAP];
        int cnt = 0;
        #pragma unroll
        for (int p = 0; p < 6; ++p) {
            int m = mm[p] ? min((int)q0[p].x, 31) : 0;
            int yb = yb0 + (p & 1);
            int dzk = (p / 2) * 9;
            auto scan_entry = [&](uint32_t e, int slot) {
                if (slot > m) return;
                int ey = (yb << 1) + (int)(e >> 29);
                int ex = (int)((e >> 18) & 0x7FFu);
                int dy = ey - y, dx = ex - x;
                if ((unsigned)(dy + 1) > 2u || (unsigned)(dx + 1) > 2u) return;
                uint32_t idx = e & 0x3FFFFu;
                if (idx == (uint32_t)n) return;
                int k = dzk + (dy + 1) * 3 + (dx + 1);
                if (cnt < PCAP) lpairs[cnt] = ((uint32_t)k << 18) | idx;
                ++cnt;
            };
            scan_entry(q0[p].y, 1);
            scan_entry(q0[p].z, 2);
            scan_entry(q0[p].w, 3);
            for (int w = 4; w <= m; w += 4) {
                uint4 q = *(const uint4*)&bent[(size_t)bix[p] * 32 + w];
                scan_entry(q.x, w);
                scan_entry(q.y, w + 1);
                scan_entry(q.z, w + 2);
                scan_entry(q.w, w + 3);
            }
        }
        cnt = min(cnt, PCAP);
        // slot0 carries cnt (and pair0 if any); rows >=1 carry the rest
        pairs[n] = ((uint32_t)cnt << 24) | (cnt ? (lpairs[0] & 0xFFFFFFu) : 0u);
        for (int c = 1; c < cnt; ++c) pairs[(size_t)c * N + n] = lpairs[c];
        for (int c = 0; c < cnt; ++c) {
            uint32_t pr = lpairs[c];
            int k = (int)(pr >> 18), idx = (int)(pr & 0x3FFFFu);
            float g0 = feat[idx * 3 + 0], g1 = feat[idx * 3 + 1], g2 = feat[idx * 3 + 2];
            const float* wk = w1 + k * 48;     // L1-resident (5.2 KB)
            #pragma unroll
            for (int d = 0; d < 16; ++d)
                acc[d] = fmaf(g0, wk[d], fmaf(g1, wk[16 + d], fmaf(g2, wk[32 + d], acc[d])));
        }
    }
    // staged coalesced h1 store (h1 has slack past N)
    #pragma unroll
    for (int r = 0; r < 4; ++r)
        stage[threadIdx.x * 4 + r] = make_float4(acc[r * 4], acc[r * 4 + 1],
                                                 acc[r * 4 + 2], acc[r * 4 + 3]);
    __syncthreads();
    {
        float4* o4 = (float4*)h1;
        size_t base = (size_t)blockIdx.x * 1024;
        #pragma unroll
        for (int r = 0; r < 4; ++r)
            o4[base + r * 256 + threadIdx.x] = stage[r * 256 + threadIdx.x];
    }
    __syncthreads();
    stats_epilogue(acc, partials, sred);
}

// ------- finalize1: parallel reduce partials -> scale/shift (for conv2) -------
__global__ void k_finalize(const float* __restrict__ partials, int nb,
                           const float* __restrict__ gamma, const float* __restrict__ beta,
                           float* __restrict__ scsh, float invN) {
    __shared__ float red[32][33];
    int ch = threadIdx.x & 31;
    int rg = threadIdx.x >> 5;   // 0..31
    float s0 = 0.f, s1 = 0.f, s2 = 0.f, s3 = 0.f;
    int j = rg;
    for (; j + 96 < nb; j += 128) {
        s0 += partials[(size_t)(j      ) * 32 + ch];
        s1 += partials[(size_t)(j + 32 ) * 32 + ch];
        s2 += partials[(size_t)(j + 64 ) * 32 + ch];
        s3 += partials[(size_t)(j + 96 ) * 32 + ch];
    }
    for (; j < nb; j += 32) s0 += partials[(size_t)j * 32 + ch];
    red[rg][ch] = (s0 + s1) + (s2 + s3);
    __syncthreads();
    if (threadIdx.x < 32) {
        float t = 0.f;
        #pragma unroll
        for (int r = 0; r < 32; ++r) t += red[r][threadIdx.x];
        red[0][threadIdx.x] = t;
    }
    __syncthreads();
    if (threadIdx.x < 16) {
        int d = threadIdx.x;
        float mean = red[0][d] * invN;
        float var = red[0][16 + d] * invN - mean * mean;
        float s2c = gamma[d] * rsqrtf(var + BN_EPS);
        scsh[d] = s2c;
        scsh[16 + d] = beta[d] - mean * s2c;
    }
}

// ------- conv2: staged coalesced self-load/store, BN1+ReLU fused, BN2 stats -------
__global__ void k_conv2(const float* __restrict__ h1, const uint32_t* __restrict__ pairs,
                        const float* __restrict__ w2, const float* __restrict__ scsh1,
                        float* __restrict__ out, float* __restrict__ partials, int N) {
    __shared__ float sred[4][32];
    __shared__ float4 stage[256 * 4];      // 16 KB tile (reused for load then store)
    __shared__ float sc[16], sh[16];
    if (threadIdx.x < 16) { sc[threadIdx.x] = scsh1[threadIdx.x]; sh[threadIdx.x] = scsh1[16 + threadIdx.x]; }
    // staged coalesced self h1 load (slack past N)
    {
        const float4* i4 = (const float4*)h1;
        size_t base = (size_t)blockIdx.x * 1024;
        #pragma unroll
        for (int r = 0; r < 4; ++r)
            stage[r * 256 + threadIdx.x] = i4[base + r * 256 + threadIdx.x];
    }
    __syncthreads();
    int n = blockIdx.x * blockDim.x + threadIdx.x;
    float acc[16];
    #pragma unroll
    for (int d = 0; d < 16; ++d) acc[d] = 0.f;
    if (n < N) {
        float g[16];
        #pragma unroll
        for (int cb = 0; cb < 4; ++cb) {
            float4 t = stage[threadIdx.x * 4 + cb];
            g[cb * 4 + 0] = fmaxf(fmaf(t.x, sc[cb * 4 + 0], sh[cb * 4 + 0]), 0.f);
            g[cb * 4 + 1] = fmaxf(fmaf(t.y, sc[cb * 4 + 1], sh[cb * 4 + 1]), 0.f);
            g[cb * 4 + 2] = fmaxf(fmaf(t.z, sc[cb * 4 + 2], sh[cb * 4 + 2]), 0.f);
            g[cb * 4 + 3] = fmaxf(fmaf(t.w, sc[cb * 4 + 3], sh[cb * 4 + 3]), 0.f);
        }
        {
            const float* w = w2 + 13 * 256;    // uniform -> scalar-cache loads
            #pragma unroll
            for (int c = 0; c < 16; ++c)
                #pragma unroll
                for (int d = 0; d < 16; ++d)
                    acc[d] = fmaf(g[c], w[c * 16 + d], acc[d]);
        }
        uint32_t p0 = pairs[n];
        int m = (int)(p0 >> 24);
        uint32_t pr = p0 & 0xFFFFFFu;
        for (int cc = 0; cc < m; ++cc) {
            if (cc > 0) pr = pairs[(size_t)cc * N + n];
            int k = (int)((pr >> 18) & 0x1Fu), idx = (int)(pr & 0x3FFFFu);
            #pragma unroll
            for (int c = 0; c < 16; c += 4) {
                float4 t = *(const float4*)&h1[(size_t)idx * 16 + c];
                g[c]     = fmaxf(fmaf(t.x, sc[c],     sh[c]),     0.f);
                g[c + 1] = fmaxf(fmaf(t.y, sc[c + 1], sh[c + 1]), 0.f);
                g[c + 2] = fmaxf(fmaf(t.z, sc[c + 2], sh[c + 2]), 0.f);
                g[c + 3] = fmaxf(fmaf(t.w, sc[c + 3], sh[c + 3]), 0.f);
            }
            const float* wk = w2 + k * 256;    // L1-resident (27.6 KB)
            #pragma unroll
            for (int c = 0; c < 16; ++c)
                #pragma unroll
                for (int d = 0; d < 16; ++d)
                    acc[d] = fmaf(g[c], wk[c * 16 + d], acc[d]);
        }
    }
    // staged coalesced out store (guarded: out has exactly N*16 floats)
    #pragma unroll
    for (int r = 0; r < 4; ++r)
        stage[threadIdx.x * 4 + r] = make_float4(acc[r * 4], acc[r * 4 + 1],
                                                 acc[r * 4 + 2], acc[r * 4 + 3]);
    __syncthreads();
    {
        float4* o4 = (float4*)out;
        size_t base = (size_t)blockIdx.x * 1024;
        int lim = N * 4;
        #pragma unroll
        for (int r = 0; r < 4; ++r) {
            size_t gi = base + r * 256 + threadIdx.x;
            if (gi < (size_t)lim) o4[gi] = stage[r * 256 + threadIdx.x];
        }
    }
    __syncthreads();
    stats_epilogue(acc, partials, sred);
}

// ------- bnrelu: fused redundant BN2 finalize + grid-stride normalize -------
__global__ void k_bnrelu(float* __restrict__ out, const float* __restrict__ partials2,
                         int nbp, const float* __restrict__ gamma2,
                         const float* __restrict__ beta2, float invN, int nvec) {
    __shared__ float red[8][33];
    __shared__ float scsh[32];
    reduce_scsh(partials2, nbp, gamma2, beta2, invN, red, scsh);
    int stride = gridDim.x * blockDim.x;
    for (int i = blockIdx.x * blockDim.x + threadIdx.x; i < nvec; i += stride) {
        float4 v = ((float4*)out)[i];
        int c0 = (i & 3) * 4;
        v.x = fmaxf(fmaf(v.x, scsh[c0 + 0], scsh[16 + c0 + 0]), 0.f);
        v.y = fmaxf(fmaf(v.y, scsh[c0 + 1], scsh[16 + c0 + 1]), 0.f);
        v.z = fmaxf(fmaf(v.z, scsh[c0 + 2], scsh[16 + c0 + 2]), 0.f);
        v.w = fmaxf(fmaf(v.w, scsh[c0 + 3], scsh[16 + c0 + 3]), 0.f);
        ((float4*)out)[i] = v;
    }
}

extern "C" void kernel_launch(void* const* d_in, const int* in_sizes, int n_in,
                              void* d_out, int out_size, void* d_ws, size_t ws_size,
                              hipStream_t stream) {
    const float* feat   = (const float*)d_in[0];
    const int*   coords = (const int*)d_in[1];
    const float* w1     = (const float*)d_in[2];
    const float* gamma1 = (const float*)d_in[3];
    const float* beta1  = (const float*)d_in[4];
    const float* w2     = (const float*)d_in[5];
    const float* gamma2 = (const float*)d_in[6];
    const float* beta2  = (const float*)d_in[7];
    float* out = (float*)d_out;
    const int N = in_sizes[0] / 3;

    const int T = 256;
    const int nb = (N + T - 1) / T;          // 782 blocks
    const int nvec = N * 16 / 4;
    const float invN = 1.f / (float)N;

    // workspace layout (64B aligned)
    char* ws = (char*)d_ws;
    size_t off = 0;
    uint32_t* bent = (uint32_t*)(ws + off);  off += (size_t)NBUCKET * 32 * 4;        // 4.2 MB
    uint32_t* pairs = (uint32_t*)(ws + off); off += (size_t)PCAP * N * 4;            // 9.6 MB
    float* h1 = (float*)(ws + off);          off += (size_t)(nb * T) * 16 * 4;       // 12.8 MB + slack
    float* partials1 = (float*)(ws + off);   off += ((size_t)nb * 32 * 4 + 63) & ~(size_t)63;
    float* partials2 = (float*)(ws + off);   off += ((size_t)nb * 32 * 4 + 63) & ~(size_t)63;
    float* stats = (float*)(ws + off);       // [0:32] sc/sh 1

    hipMemsetAsync(bent, 0, (size_t)NBUCKET * 32 * 4, stream);
    k_insert<<<nb, T, 0, stream>>>(coords, bent, N);
    k_build_conv1<<<nb, T, 0, stream>>>(coords, bent, feat, w1, pairs, h1, partials1, N);
    k_finalize<<<1, 1024, 0, stream>>>(partials1, nb, gamma1, beta1, stats, invN);
    k_conv2<<<nb, T, 0, stream>>>(h1, pairs, w2, stats, out, partials2, N);
    k_bnrelu<<<128, T, 0, stream>>>(out, partials2, nb, gamma2, beta2, invN, nvec);
}

// Round 10
// 155.187 us; speedup vs baseline: 1.0548x; 1.0548x over previous
//
#include <hip/hip_runtime.h>
#include <stdint.h>

#define SPARSE_D 41
#define SPARSE_H 1600
#define SPARSE_W 1408
#define BN_EPS 0.001f

static constexpr int NYB = SPARSE_H / 2;          // 800
static constexpr int NBUCKET = SPARSE_D * NYB;    // 32,800
static constexpr int PCAP = 12;                   // max non-self pairs per voxel (lambda~0.056)

// bucket = z*NYB + (y>>1): 32 uint32 words (128B). word0 = count, words 1..31 = entries.
// entry: [29]=y&1, [28:18]=x (11b), [17:0]=idx
// pairs slot0 word (always written): [27:24]=cnt, [22:18]=k, [17:0]=idx
// pairs rows >=1 (written when cnt>1):       [22:18]=k, [17:0]=idx

// ---------------- scatter voxels into buckets (count in word0) ----------------
__global__ void k_insert(const int* __restrict__ coords, uint32_t* __restrict__ bent, int N) {
    int n = blockIdx.x * blockDim.x + threadIdx.x;
    if (n >= N) return;
    int4 c4 = ((const int4*)coords)[n];
    int z = c4.y, y = c4.z, x = c4.w;
    int b = z * NYB + (y >> 1);
    uint32_t e = ((uint32_t)(y & 1) << 29) | ((uint32_t)x << 18) | (uint32_t)n;
    int slot = atomicAdd((int*)&bent[(size_t)b * 32], 1) + 1;
    if (slot <= 31) bent[(size_t)b * 32 + slot] = e;
}

// ---- stats epilogue: wave shuffle reduce -> LDS -> per-block partials ----
__device__ __forceinline__ void stats_epilogue(const float acc[16],
                                               float* __restrict__ partials,
                                               float (*sred)[32]) {
    int lid = threadIdx.x & 63;
    int wid = threadIdx.x >> 6;
    #pragma unroll
    for (int d = 0; d < 16; ++d) {
        float v = acc[d];
        float v2 = v * v;
        #pragma unroll
        for (int off = 32; off; off >>= 1) {
            v += __shfl_xor(v, off);
            v2 += __shfl_xor(v2, off);
        }
        if (lid == 0) { sred[wid][d] = v; sred[wid][16 + d] = v2; }
    }
    __syncthreads();
    if (threadIdx.x < 32)
        partials[(size_t)blockIdx.x * 32 + threadIdx.x] =
            sred[0][threadIdx.x] + sred[1][threadIdx.x] +
            sred[2][threadIdx.x] + sred[3][threadIdx.x];
}

// ------ fused: build pairs (regs) + conv1 (C=3->16, weights from global) + BN1 stats ------
__global__ void k_build_conv1(const int* __restrict__ coords, const uint32_t* __restrict__ bent,
                              const float* __restrict__ feat, const float* __restrict__ w1,
                              uint32_t* __restrict__ pairs,
                              float* __restrict__ h1, float* __restrict__ partials, int N) {
    __shared__ float sred[4][32];
    int n = blockIdx.x * blockDim.x + threadIdx.x;
    float acc[16];
    #pragma unroll
    for (int d = 0; d < 16; ++d) acc[d] = 0.f;
    if (n < N) {
        int4 c4 = ((const int4*)coords)[n];
        int z = c4.y, y = c4.z, x = c4.w;

        // self term first (uniform weight pointer -> scalar loads; overlaps with probes)
        float f0 = feat[n * 3 + 0], f1 = feat[n * 3 + 1], f2 = feat[n * 3 + 2];
        const float* wd = w1 + 13 * 48;
        #pragma unroll
        for (int d = 0; d < 16; ++d)
            acc[d] = fmaf(f0, wd[d], fmaf(f1, wd[16 + d], f2 * wd[32 + d]));

        // preload all 6 bucket line0s unconditionally (masked -> bucket 0) for MLP
        int yb0 = (y - 1) >> 1;
        uint4 q0[6];
        int bix[6], mm[6];
        #pragma unroll
        for (int p = 0; p < 6; ++p) {
            int zz = z + p / 2 - 1;
            int yb = yb0 + (p & 1);
            bool v = ((unsigned)zz < SPARSE_D) & ((unsigned)yb < NYB);
            int b = v ? (zz * NYB + yb) : 0;
            bix[p] = b;
            q0[p] = *(const uint4*)&bent[(size_t)b * 32];
            mm[p] = v ? 1 : 0;
        }

        uint32_t lpairs[PCAP];
        int cnt = 0;
        #pragma unroll
        for (int p = 0; p < 6; ++p) {
            int m = mm[p] ? min((int)q0[p].x, 31) : 0;
            int yb = yb0 + (p & 1);
            int dzk = (p / 2) * 9;
            auto scan_entry = [&](uint32_t e, int slot) {
                if (slot > m) return;
                int ey = (yb << 1) + (int)(e >> 29);
                int ex = (int)((e >> 18) & 0x7FFu);
                int dy = ey - y, dx = ex - x;
                if ((unsigned)(dy + 1) > 2u || (unsigned)(dx + 1) > 2u) return;
                uint32_t idx = e & 0x3FFFFu;
                if (idx == (uint32_t)n) return;
                int k = dzk + (dy + 1) * 3 + (dx + 1);
                if (cnt < PCAP) lpairs[cnt] = ((uint32_t)k << 18) | idx;
                ++cnt;
            };
            scan_entry(q0[p].y, 1);
            scan_entry(q0[p].z, 2);
            scan_entry(q0[p].w, 3);
            for (int w = 4; w <= m; w += 4) {
                uint4 q = *(const uint4*)&bent[(size_t)bix[p] * 32 + w];
                scan_entry(q.x, w);
                scan_entry(q.y, w + 1);
                scan_entry(q.z, w + 2);
                scan_entry(q.w, w + 3);
            }
        }
        cnt = min(cnt, PCAP);
        // slot0 always written: cnt in [27:24] + pair0 (if any); rows >=1 carry the rest
        pairs[n] = ((uint32_t)cnt << 24) | (cnt ? (lpairs[0] & 0xFFFFFFu) : 0u);
        for (int c = 1; c < cnt; ++c) pairs[(size_t)c * N + n] = lpairs[c];
        for (int c = 0; c < cnt; ++c) {
            uint32_t pr = lpairs[c];
            int k = (int)((pr >> 18) & 0x1Fu), idx = (int)(pr & 0x3FFFFu);
            float g0 = feat[idx * 3 + 0], g1 = feat[idx * 3 + 1], g2 = feat[idx * 3 + 2];
            const float* wk = w1 + k * 48;     // L1-resident (5.2 KB total)
            #pragma unroll
            for (int d = 0; d < 16; ++d)
                acc[d] = fmaf(g0, wk[d], fmaf(g1, wk[16 + d], fmaf(g2, wk[32 + d], acc[d])));
        }
        float4* o = (float4*)&h1[(size_t)n * 16];
        o[0] = make_float4(acc[0], acc[1], acc[2], acc[3]);
        o[1] = make_float4(acc[4], acc[5], acc[6], acc[7]);
        o[2] = make_float4(acc[8], acc[9], acc[10], acc[11]);
        o[3] = make_float4(acc[12], acc[13], acc[14], acc[15]);
    }
    stats_epilogue(acc, partials, sred);
}

// ------- conv2: C=16->16, weights from global/L1, BN1+ReLU fused on load -------
__global__ void k_conv2(const float* __restrict__ h1, const uint32_t* __restrict__ pairs,
                        const float* __restrict__ w2, const float* __restrict__ scsh1,
                        float* __restrict__ out, float* __restrict__ partials, int N) {
    __shared__ float sred[4][32];
    __shared__ float sc[16], sh[16];
    if (threadIdx.x < 16) { sc[threadIdx.x] = scsh1[threadIdx.x]; sh[threadIdx.x] = scsh1[16 + threadIdx.x]; }
    __syncthreads();
    int n = blockIdx.x * blockDim.x + threadIdx.x;
    float acc[16];
    #pragma unroll
    for (int d = 0; d < 16; ++d) acc[d] = 0.f;
    if (n < N) {
        float g[16];
        #pragma unroll
        for (int c = 0; c < 16; c += 4) {
            float4 t = *(const float4*)&h1[(size_t)n * 16 + c];
            g[c]     = fmaxf(fmaf(t.x, sc[c],     sh[c]),     0.f);
            g[c + 1] = fmaxf(fmaf(t.y, sc[c + 1], sh[c + 1]), 0.f);
            g[c + 2] = fmaxf(fmaf(t.z, sc[c + 2], sh[c + 2]), 0.f);
            g[c + 3] = fmaxf(fmaf(t.w, sc[c + 3], sh[c + 3]), 0.f);
        }
        {
            const float* w = w2 + 13 * 256;    // uniform -> scalar-cache loads
            #pragma unroll
            for (int c = 0; c < 16; ++c)
                #pragma unroll
                for (int d = 0; d < 16; ++d)
                    acc[d] = fmaf(g[c], w[c * 16 + d], acc[d]);
        }
        uint32_t p0 = pairs[n];
        int m = (int)(p0 >> 24);
        uint32_t pr = p0 & 0xFFFFFFu;
        for (int cc = 0; cc < m; ++cc) {
            if (cc > 0) pr = pairs[(size_t)cc * N + n];
            int k = (int)((pr >> 18) & 0x1Fu), idx = (int)(pr & 0x3FFFFu);
            #pragma unroll
            for (int c = 0; c < 16; c += 4) {
                float4 t = *(const float4*)&h1[(size_t)idx * 16 + c];
                g[c]     = fmaxf(fmaf(t.x, sc[c],     sh[c]),     0.f);
                g[c + 1] = fmaxf(fmaf(t.y, sc[c + 1], sh[c + 1]), 0.f);
                g[c + 2] = fmaxf(fmaf(t.z, sc[c + 2], sh[c + 2]), 0.f);
                g[c + 3] = fmaxf(fmaf(t.w, sc[c + 3], sh[c + 3]), 0.f);
            }
            const float* wk = w2 + k * 256;    // L1-resident (27.6 KB total)
            #pragma unroll
            for (int c = 0; c < 16; ++c)
                #pragma unroll
                for (int d = 0; d < 16; ++d)
                    acc[d] = fmaf(g[c], wk[c * 16 + d], acc[d]);
        }
        float4* o = (float4*)&out[(size_t)n * 16];
        o[0] = make_float4(acc[0], acc[1], acc[2], acc[3]);
        o[1] = make_float4(acc[4], acc[5], acc[6], acc[7]);
        o[2] = make_float4(acc[8], acc[9], acc[10], acc[11]);
        o[3] = make_float4(acc[12], acc[13], acc[14], acc[15]);
    }
    stats_epilogue(acc, partials, sred);
}

// ------- finalize: 1024 threads, 32 row-groups x 32 channels, 4-way ILP -------
__global__ void k_finalize(const float* __restrict__ partials, int nb,
                           const float* __restrict__ gamma, const float* __restrict__ beta,
                           float* __restrict__ scsh, float invN) {
    __shared__ float red[32][33];
    int ch = threadIdx.x & 31;
    int rg = threadIdx.x >> 5;   // 0..31
    float s0 = 0.f, s1 = 0.f, s2 = 0.f, s3 = 0.f;
    int j = rg;
    for (; j + 96 < nb; j += 128) {
        s0 += partials[(size_t)(j      ) * 32 + ch];
        s1 += partials[(size_t)(j + 32 ) * 32 + ch];
        s2 += partials[(size_t)(j + 64 ) * 32 + ch];
        s3 += partials[(size_t)(j + 96 ) * 32 + ch];
    }
    for (; j < nb; j += 32) s0 += partials[(size_t)j * 32 + ch];
    red[rg][ch] = (s0 + s1) + (s2 + s3);
    __syncthreads();
    if (threadIdx.x < 32) {
        float t = 0.f;
        #pragma unroll
        for (int r = 0; r < 32; ++r) t += red[r][threadIdx.x];
        red[0][threadIdx.x] = t;
    }
    __syncthreads();
    if (threadIdx.x < 16) {
        int d = threadIdx.x;
        float mean = red[0][d] * invN;
        float var = red[0][16 + d] * invN - mean * mean;
        float s2c = gamma[d] * rsqrtf(var + BN_EPS);
        scsh[d] = s2c;
        scsh[16 + d] = beta[d] - mean * s2c;
    }
}

// ---------------- elementwise BN+ReLU (float4 per thread) ----------------
__global__ void k_bnrelu4(float* __restrict__ x, const float* __restrict__ scsh, int nvec) {
    __shared__ float sc[16], sh[16];
    if (threadIdx.x < 16) { sc[threadIdx.x] = scsh[threadIdx.x]; sh[threadIdx.x] = scsh[16 + threadIdx.x]; }
    __syncthreads();
    int i = blockIdx.x * blockDim.x + threadIdx.x;
    if (i < nvec) {
        float4 v = ((float4*)x)[i];
        int c0 = (i & 3) * 4;
        v.x = fmaxf(fmaf(v.x, sc[c0 + 0], sh[c0 + 0]), 0.f);
        v.y = fmaxf(fmaf(v.y, sc[c0 + 1], sh[c0 + 1]), 0.f);
        v.z = fmaxf(fmaf(v.z, sc[c0 + 2], sh[c0 + 2]), 0.f);
        v.w = fmaxf(fmaf(v.w, sc[c0 + 3], sh[c0 + 3]), 0.f);
        ((float4*)x)[i] = v;
    }
}

extern "C" void kernel_launch(void* const* d_in, const int* in_sizes, int n_in,
                              void* d_out, int out_size, void* d_ws, size_t ws_size,
                              hipStream_t stream) {
    const float* feat   = (const float*)d_in[0];
    const int*   coords = (const int*)d_in[1];
    const float* w1     = (const float*)d_in[2];
    const float* gamma1 = (const float*)d_in[3];
    const float* beta1  = (const float*)d_in[4];
    const float* w2     = (const float*)d_in[5];
    const float* gamma2 = (const float*)d_in[6];
    const float* beta2  = (const float*)d_in[7];
    float* out = (float*)d_out;
    const int N = in_sizes[0] / 3;

    const int T = 256;
    const int nb = (N + T - 1) / T;          // 782 blocks
    const int nvec = N * 16 / 4;
    const int nbv = (nvec + T - 1) / T;

    // workspace layout (64B aligned)
    char* ws = (char*)d_ws;
    size_t off = 0;
    uint32_t* bent = (uint32_t*)(ws + off);  off += (size_t)NBUCKET * 32 * 4;        // 4.2 MB
    uint32_t* pairs = (uint32_t*)(ws + off); off += (size_t)PCAP * N * 4;            // 9.6 MB
    float* h1 = (float*)(ws + off);          off += (size_t)N * 16 * 4;              // 12.8 MB
    float* partials = (float*)(ws + off);    off += ((size_t)nb * 32 * 4 + 63) & ~(size_t)63;
    float* stats = (float*)(ws + off);       // [0:32] sc/sh 1, [32:64] sc/sh 2

    hipMemsetAsync(bent, 0, (size_t)NBUCKET * 32 * 4, stream);
    k_insert<<<nb, T, 0, stream>>>(coords, bent, N);
    k_build_conv1<<<nb, T, 0, stream>>>(coords, bent, feat, w1, pairs, h1, partials, N);
    k_finalize<<<1, 1024, 0, stream>>>(partials, nb, gamma1, beta1, stats, 1.f / (float)N);
    k_conv2<<<nb, T, 0, stream>>>(h1, pairs, w2, stats, out, partials, N);
    k_finalize<<<1, 1024, 0, stream>>>(partials, nb, gamma2, beta2, stats + 32, 1.f / (float)N);
    k_bnrelu4<<<nbv, T, 0, stream>>>(out, stats + 32, nvec);
}